// Round 1
// baseline (49.741 us; speedup 1.0000x reference)
//
#include <hip/hip_runtime.h>

typedef float f4 __attribute__((ext_vector_type(4)));
typedef int   i4 __attribute__((ext_vector_type(4)));

#define NOBJ 64

__global__ __launch_bounds__(256) void compose_kernel(
    const float* __restrict__ trans,    // [NOBJ,3]
    const float* __restrict__ rotors,   // [NOBJ,4]
    const float* __restrict__ means,    // [M,3]
    const float* __restrict__ quats,    // [M,4]
    const int*   __restrict__ indices,  // [M]
    float* __restrict__ out,            // [M*3] means ++ [M*4] quats
    int M)
{
    // Stage object table: [obj][0] = rotor (w,x,y,z), [obj][1] = trans (x,y,z,0)
    __shared__ f4 s_obj[NOBJ][2];
    const int tid = threadIdx.x;
    if (tid < NOBJ) {
        s_obj[tid][0] = ((const f4*)rotors)[tid];
        f4 tr;
        tr.x = trans[tid * 3 + 0];
        tr.y = trans[tid * 3 + 1];
        tr.z = trans[tid * 3 + 2];
        tr.w = 0.0f;
        s_obj[tid][1] = tr;
    }
    __syncthreads();

    float* out_means = out;
    float* out_quats = out + (size_t)M * 3;

    const int nquads  = M >> 2;           // points processed 4-at-a-time
    const int gstride = gridDim.x * blockDim.x;

    for (int t = blockIdx.x * blockDim.x + tid; t < nquads; t += gstride) {
        // 4 points' means: 3 x float4 (48 B, 16B-aligned)
        f4 m0 = ((const f4*)means)[t * 3 + 0];
        f4 m1 = ((const f4*)means)[t * 3 + 1];
        f4 m2 = ((const f4*)means)[t * 3 + 2];
        // 4 points' quats: 4 x float4
        f4 qin0 = ((const f4*)quats)[t * 4 + 0];
        f4 qin1 = ((const f4*)quats)[t * 4 + 1];
        f4 qin2 = ((const f4*)quats)[t * 4 + 2];
        f4 qin3 = ((const f4*)quats)[t * 4 + 3];
        // 4 indices
        i4 idx = ((const i4*)indices)[t];

        const float vx[4] = {m0.x, m0.w, m1.z, m2.y};
        const float vy[4] = {m0.y, m1.x, m1.w, m2.z};
        const float vz[4] = {m0.z, m1.y, m2.x, m2.w};
        const f4 qin[4] = {qin0, qin1, qin2, qin3};

        float om[12];
        f4 oq[4];

#pragma unroll
        for (int p = 0; p < 4; ++p) {
            const int id = idx[p];
            const f4 r  = s_obj[id][0];
            const f4 tr = s_obj[id][1];
            const float rw = r.x, rx = r.y, ry = r.z, rz = r.w;

            // quat_rotate: t2 = 2*cross(r.xyz, v); o = v + w*t2 + cross(r.xyz, t2) + trans
            const float t2x = 2.0f * (ry * vz[p] - rz * vy[p]);
            const float t2y = 2.0f * (rz * vx[p] - rx * vz[p]);
            const float t2z = 2.0f * (rx * vy[p] - ry * vx[p]);
            om[p * 3 + 0] = vx[p] + rw * t2x + (ry * t2z - rz * t2y) + tr.x;
            om[p * 3 + 1] = vy[p] + rw * t2y + (rz * t2x - rx * t2z) + tr.y;
            om[p * 3 + 2] = vz[p] + rw * t2z + (rx * t2y - ry * t2x) + tr.z;

            // quat_mul(r, q)
            const float bw = qin[p].x, bx = qin[p].y, by = qin[p].z, bz = qin[p].w;
            f4 o;
            o.x = rw * bw - rx * bx - ry * by - rz * bz;
            o.y = rw * bx + rx * bw + ry * bz - rz * by;
            o.z = rw * by - rx * bz + ry * bw + rz * bx;
            o.w = rw * bz + rx * by - ry * bx + rz * bw;
            oq[p] = o;
        }

        f4 s0 = {om[0], om[1], om[2],  om[3]};
        f4 s1 = {om[4], om[5], om[6],  om[7]};
        f4 s2 = {om[8], om[9], om[10], om[11]};
        ((f4*)out_means)[t * 3 + 0] = s0;
        ((f4*)out_means)[t * 3 + 1] = s1;
        ((f4*)out_means)[t * 3 + 2] = s2;
        ((f4*)out_quats)[t * 4 + 0] = oq[0];
        ((f4*)out_quats)[t * 4 + 1] = oq[1];
        ((f4*)out_quats)[t * 4 + 2] = oq[2];
        ((f4*)out_quats)[t * 4 + 3] = oq[3];
    }

    // Tail (M % 4 != 0) — scalar path, first threads of the grid.
    const int tail = M & 3;
    if (tail) {
        const int g = blockIdx.x * blockDim.x + tid;
        if (g < tail) {
            const int i  = nquads * 4 + g;
            const int id = indices[i];
            const f4 r  = s_obj[id][0];
            const f4 tr = s_obj[id][1];
            const float rw = r.x, rx = r.y, ry = r.z, rz = r.w;
            const float vx_ = means[i * 3 + 0];
            const float vy_ = means[i * 3 + 1];
            const float vz_ = means[i * 3 + 2];
            const float t2x = 2.0f * (ry * vz_ - rz * vy_);
            const float t2y = 2.0f * (rz * vx_ - rx * vz_);
            const float t2z = 2.0f * (rx * vy_ - ry * vx_);
            out_means[i * 3 + 0] = vx_ + rw * t2x + (ry * t2z - rz * t2y) + tr.x;
            out_means[i * 3 + 1] = vy_ + rw * t2y + (rz * t2x - rx * t2z) + tr.y;
            out_means[i * 3 + 2] = vz_ + rw * t2z + (rx * t2y - ry * t2x) + tr.z;
            const float bw = quats[i * 4 + 0], bx = quats[i * 4 + 1];
            const float by = quats[i * 4 + 2], bz = quats[i * 4 + 3];
            out_quats[i * 4 + 0] = rw * bw - rx * bx - ry * by - rz * bz;
            out_quats[i * 4 + 1] = rw * bx + rx * bw + ry * bz - rz * by;
            out_quats[i * 4 + 2] = rw * by - rx * bz + ry * bw + rz * bx;
            out_quats[i * 4 + 3] = rw * bz + rx * by - ry * bx + rz * bw;
        }
    }
}

extern "C" void kernel_launch(void* const* d_in, const int* in_sizes, int n_in,
                              void* d_out, int out_size, void* d_ws, size_t ws_size,
                              hipStream_t stream) {
    const float* trans   = (const float*)d_in[0];
    const float* rotors  = (const float*)d_in[1];
    const float* means   = (const float*)d_in[2];
    const float* quats   = (const float*)d_in[3];
    const int*   indices = (const int*)d_in[4];
    const int M = in_sizes[4];
    float* out = (float*)d_out;

    const int threads = 256;
    int nquads = M >> 2;
    if (nquads < 1) nquads = 1;
    int blocks = (nquads + threads - 1) / threads;

    compose_kernel<<<blocks, threads, 0, stream>>>(trans, rotors, means, quats,
                                                   indices, out, M);
}